// Round 1
// baseline (655.955 us; speedup 1.0000x reference)
//
#include <hip/hip_runtime.h>

typedef __attribute__((ext_vector_type(8))) __bf16 bf16x8;
typedef __attribute__((ext_vector_type(4))) float f32x4;
typedef unsigned short u16;

// Problem constants
#define TSEQ   2048
#define NB     4
#define NHEAD  16
#define HDIM   64
#define CMODEL 1024
#define MTOK   (NB*TSEQ)          // 8192 tokens

__device__ __forceinline__ u16 f2bf(float x){
  unsigned u = __float_as_uint(x);
  u += 0x7fffu + ((u >> 16) & 1u);          // RNE (no NaN inputs here)
  return (u16)(u >> 16);
}

// async global->LDS, 16B per lane. lds_base must be wave-uniform; HW writes lane i at base + i*16.
__device__ __forceinline__ void async16(const void* g, const u16* lds_base){
  __builtin_amdgcn_global_load_lds(
      (const __attribute__((address_space(1))) unsigned*)(uintptr_t)g,
      (__attribute__((address_space(3))) unsigned*)(unsigned)(uintptr_t)lds_base,
      16, 0, 0);
}

// ---------------------------------------------------------------------------
// prep kernels
// ---------------------------------------------------------------------------
__global__ void cast_bf16_kernel(const float* __restrict__ src, u16* __restrict__ dst, int n4){
  int i = blockIdx.x * blockDim.x + threadIdx.x;
  int stride = gridDim.x * blockDim.x;
  for (; i < n4; i += stride){
    float4 v = ((const float4*)src)[i];
    ((ushort4*)dst)[i] = make_ushort4(f2bf(v.x), f2bf(v.y), f2bf(v.z), f2bf(v.w));
  }
}

__global__ void rope_table_kernel(float2* __restrict__ rope){
  int i = blockIdx.x * blockDim.x + threadIdx.x;       // T * HDIM/2 = 2048*32
  if (i >= TSEQ * (HDIM/2)) return;
  int t = i >> 5, j = i & 31;
  // theta = 10000^(-2j/64) = 2^(-j * log2(10000)/32)
  float theta = exp2f(-(float)j * (13.287712379549449f / 32.f));
  float ang = (float)t * theta;
  rope[i] = make_float2(cosf(ang), sinf(ang));
}

// ---------------------------------------------------------------------------
// 128x128 tile GEMM mainloop, C = A(MxK) * B(NxK)^T, bf16, m97 structure.
// BK=32. LDS staged via global_load_lds width 16, source pre-swizzled
// (chunk p of row r holds logical k-chunk p ^ ((r>>1)&3)) so frag ds_read_b128
// lands 2-way-max on banks (free per m136). 2 barriers / K-step.
// ---------------------------------------------------------------------------
__device__ __forceinline__ void gemm128_mainloop(
    const u16* __restrict__ A, const u16* __restrict__ B,
    int m0, int n0, int K, u16* sA, u16* sB, f32x4 acc[4][4])
{
  const int tid = threadIdx.x;
  const int w = tid >> 6, lane = tid & 63;
  const int ln = lane & 15, g = lane >> 4;
  const int wm = w >> 1, wn = w & 1;

  const f32x4 zero = {0.f, 0.f, 0.f, 0.f};
#pragma unroll
  for (int mt = 0; mt < 4; ++mt)
#pragma unroll
    for (int nt = 0; nt < 4; ++nt) acc[mt][nt] = zero;

  for (int k0 = 0; k0 < K; k0 += 32){
    __syncthreads();                       // previous tile fully consumed
#pragma unroll
    for (int i = 0; i < 2; ++i){
      int c = i*256 + tid;                 // chunk id 0..511
      int r = c >> 2, p = c & 3;
      int ks = p ^ ((r >> 1) & 3);         // pre-swizzled source k-chunk
      async16(A + (size_t)(m0 + r)*K + k0 + ks*8, sA + (size_t)(i*256 + w*64)*8);
      async16(B + (size_t)(n0 + r)*K + k0 + ks*8, sB + (size_t)(i*256 + w*64)*8);
    }
    __syncthreads();                       // drains vmcnt -> LDS ready

    bf16x8 af[4], bfr[4];
#pragma unroll
    for (int mt = 0; mt < 4; ++mt){
      int row = wm*64 + mt*16 + ln;
      int p = g ^ ((row >> 1) & 3);
      af[mt] = *(const bf16x8*)&sA[row*32 + p*8];
    }
#pragma unroll
    for (int nt = 0; nt < 4; ++nt){
      int row = wn*64 + nt*16 + ln;
      int p = g ^ ((row >> 1) & 3);
      bfr[nt] = *(const bf16x8*)&sB[row*32 + p*8];
    }
#pragma unroll
    for (int mt = 0; mt < 4; ++mt)
#pragma unroll
      for (int nt = 0; nt < 4; ++nt)
        acc[mt][nt] = __builtin_amdgcn_mfma_f32_16x16x32_bf16(af[mt], bfr[nt], acc[mt][nt], 0, 0, 0);
  }
}

// ---------------------------------------------------------------------------
// QKV projection + bias + RoPE(Q,K) + head-split; V written transposed.
// blockIdx.z: 0=Q 1=K 2=V
// ---------------------------------------------------------------------------
__global__ __launch_bounds__(256) void gemm_qkv_kernel(
    const u16* __restrict__ xb,
    const u16* __restrict__ wqb, const u16* __restrict__ wkb, const u16* __restrict__ wvb,
    const float* __restrict__ bq, const float* __restrict__ bk, const float* __restrict__ bv,
    const float2* __restrict__ rope,
    u16* __restrict__ Qh, u16* __restrict__ Kh, u16* __restrict__ Vt)
{
  __shared__ u16 sA[128*32];
  __shared__ u16 sB[128*32];
  const int z = blockIdx.z;
  const u16*  W    = (z == 0) ? wqb : (z == 1) ? wkb : wvb;
  const float* bias = (z == 0) ? bq  : (z == 1) ? bk  : bv;
  const int m0 = blockIdx.y * 128, n0 = blockIdx.x * 128;

  f32x4 acc[4][4];
  gemm128_mainloop(xb, W, m0, n0, CMODEL, sA, sB, acc);

  const int tid = threadIdx.x, w = tid >> 6, lane = tid & 63;
  const int ln = lane & 15, g = lane >> 4;
  const int wm = w >> 1, wn = w & 1;

#pragma unroll
  for (int mt = 0; mt < 4; ++mt){
#pragma unroll
    for (int nt = 0; nt < 4; ++nt){
      int o  = n0 + wn*64 + nt*16 + ln;    // output feature 0..1023
      float bb = bias[o];
      int h  = o >> 6;
      int dd = o & 63;
      if (z < 2){
        int j = dd >> 1;
        u16* dst = (z == 0) ? Qh : Kh;
#pragma unroll
        for (int rr = 0; rr < 4; ++rr){
          int t  = m0 + wm*64 + mt*16 + g*4 + rr;   // global token
          int b  = t >> 11, tt = t & (TSEQ-1);
          float v  = acc[mt][nt][rr] + bb;
          float pv = __shfl_xor(v, 1);              // rope partner (o^1), same row
          float2 cs = rope[tt*32 + j];
          float out = ((o & 1) == 0) ? (v*cs.x - pv*cs.y) : (pv*cs.y + v*cs.x);
          dst[(size_t)((b*NHEAD + h)*TSEQ + tt)*HDIM + dd] = f2bf(out);
        }
      } else {
        int t0 = m0 + wm*64 + mt*16 + g*4;
        int b  = t0 >> 11, tt0 = t0 & (TSEQ-1);
        u16 pk[4];
#pragma unroll
        for (int rr = 0; rr < 4; ++rr) pk[rr] = f2bf(acc[mt][nt][rr] + bb);
        *(ushort4*)&Vt[(size_t)((b*NHEAD + h)*HDIM + dd)*TSEQ + tt0] =
            make_ushort4(pk[0], pk[1], pk[2], pk[3]);
      }
    }
  }
}

// ---------------------------------------------------------------------------
// Flash attention, causal. 4 waves/block, each wave owns 16 q-rows.
// K/V frags direct from global (L2-resident per head). Online softmax is
// wave-parallel (shfl over the 16-lane row group). P transposed via per-wave
// XOR-swizzled LDS (conflict-free both sides).
// ---------------------------------------------------------------------------
__global__ __launch_bounds__(256) void attn_kernel(
    const u16* __restrict__ Qh, const u16* __restrict__ Kh,
    const u16* __restrict__ Vt, u16* __restrict__ yb)
{
  __shared__ u16 plds[4][16*64];
  const int tid = threadIdx.x, w = tid >> 6, lane = tid & 63;
  const int ln = lane & 15, g = lane >> 4;
  const int bh = blockIdx.y, b = bh >> 4, h = bh & (NHEAD-1);
  const int qb = blockIdx.x*64 + w*16;

  const u16* Qbase = Qh + (size_t)bh * TSEQ * HDIM;
  const u16* Kbase = Kh + (size_t)bh * TSEQ * HDIM;
  const u16* Vbase = Vt + (size_t)bh * HDIM * TSEQ;
  u16* pw = plds[w];

  bf16x8 aq[2];
#pragma unroll
  for (int kc = 0; kc < 2; ++kc)
    aq[kc] = *(const bf16x8*)&Qbase[(size_t)(qb + ln)*HDIM + kc*32 + g*8];

  const f32x4 zero = {0.f, 0.f, 0.f, 0.f};
  f32x4 yacc[4];
#pragma unroll
  for (int dt = 0; dt < 4; ++dt) yacc[dt] = zero;
  float m2[4], l2[4];
#pragma unroll
  for (int rr = 0; rr < 4; ++rr){ m2[rr] = -1e30f; l2[rr] = 0.f; }

  const int jtmax = qb >> 6;               // == blockIdx.x for all waves
  const float SC = 0.125f * 1.44269504f;   // 1/sqrt(64) * log2(e), softmax in base 2

  for (int jt = 0; jt <= jtmax; ++jt){
    // S = Q K^T for this 64-wide kv tile
    f32x4 s[4];
#pragma unroll
    for (int nt = 0; nt < 4; ++nt){
      const u16* kr = &Kbase[(size_t)(jt*64 + nt*16 + ln)*HDIM + g*8];
      bf16x8 k0 = *(const bf16x8*)kr;
      bf16x8 k1 = *(const bf16x8*)(kr + 32);
      f32x4 t = __builtin_amdgcn_mfma_f32_16x16x32_bf16(aq[0], k0, zero, 0, 0, 0);
      s[nt]   = __builtin_amdgcn_mfma_f32_16x16x32_bf16(aq[1], k1, t,    0, 0, 0);
    }
    // scale + causal mask (only the diagonal tile needs masking)
#pragma unroll
    for (int nt = 0; nt < 4; ++nt)
#pragma unroll
      for (int rr = 0; rr < 4; ++rr){
        float v = s[nt][rr] * SC;
        if (jt == jtmax){
          int tk = jt*64 + nt*16 + ln;
          int tq = qb + g*4 + rr;
          if (tk > tq) v = -1e30f;
        }
        s[nt][rr] = v;
      }
    // wave-parallel row max
    float tm[4];
#pragma unroll
    for (int rr = 0; rr < 4; ++rr){
      tm[rr] = fmaxf(fmaxf(s[0][rr], s[1][rr]), fmaxf(s[2][rr], s[3][rr]));
    }
#pragma unroll
    for (int mk = 1; mk <= 8; mk <<= 1)
#pragma unroll
      for (int rr = 0; rr < 4; ++rr) tm[rr] = fmaxf(tm[rr], __shfl_xor(tm[rr], mk));

    float sc[4], ts[4];
#pragma unroll
    for (int rr = 0; rr < 4; ++rr){
      float mn = fmaxf(m2[rr], tm[rr]);
      sc[rr] = exp2f(m2[rr] - mn);
      m2[rr] = mn;
      ts[rr] = 0.f;
    }
#pragma unroll
    for (int nt = 0; nt < 4; ++nt)
#pragma unroll
      for (int rr = 0; rr < 4; ++rr){
        float p = exp2f(s[nt][rr] - m2[rr]);
        s[nt][rr] = p;
        ts[rr] += p;
      }
#pragma unroll
    for (int mk = 1; mk <= 8; mk <<= 1)
#pragma unroll
      for (int rr = 0; rr < 4; ++rr) ts[rr] += __shfl_xor(ts[rr], mk);
#pragma unroll
    for (int rr = 0; rr < 4; ++rr) l2[rr] = l2[rr]*sc[rr] + ts[rr];
#pragma unroll
    for (int dt = 0; dt < 4; ++dt)
#pragma unroll
      for (int rr = 0; rr < 4; ++rr) yacc[dt][rr] *= sc[rr];

    // P -> LDS (XOR-swizzled, conflict-free write & read), then PV
#pragma unroll
    for (int nt = 0; nt < 4; ++nt)
#pragma unroll
      for (int rr = 0; rr < 4; ++rr){
        int row = g*4 + rr;                       // q-row within 16
        int ec  = (nt*16 + ln) ^ ((row & 7) << 3);
        pw[row*64 + ec] = f2bf(s[nt][rr]);
      }
#pragma unroll
    for (int kc = 0; kc < 2; ++kc){
      int colbase = (kc*32 + g*8) ^ ((ln & 7) << 3);
      bf16x8 ap = *(const bf16x8*)&pw[ln*64 + colbase];
#pragma unroll
      for (int dt = 0; dt < 4; ++dt){
        bf16x8 bv = *(const bf16x8*)&Vbase[(size_t)(dt*16 + ln)*TSEQ + jt*64 + kc*32 + g*8];
        yacc[dt] = __builtin_amdgcn_mfma_f32_16x16x32_bf16(ap, bv, yacc[dt], 0, 0, 0);
      }
    }
  }

  // epilogue: divide by l, write [token][C] bf16 for the output projection
  float inv[4];
#pragma unroll
  for (int rr = 0; rr < 4; ++rr) inv[rr] = 1.0f / l2[rr];
#pragma unroll
  for (int dt = 0; dt < 4; ++dt)
#pragma unroll
    for (int rr = 0; rr < 4; ++rr){
      int tt = qb + g*4 + rr;
      int c  = h*HDIM + dt*16 + ln;
      yb[(size_t)(b*TSEQ + tt)*CMODEL + c] = f2bf(yacc[dt][rr] * inv[rr]);
    }
}

// ---------------------------------------------------------------------------
// output projection, f32 result straight to d_out
// ---------------------------------------------------------------------------
__global__ __launch_bounds__(256) void gemm_proj_kernel(
    const u16* __restrict__ yb, const u16* __restrict__ wpb,
    const float* __restrict__ bp, float* __restrict__ out)
{
  __shared__ u16 sA[128*32];
  __shared__ u16 sB[128*32];
  const int m0 = blockIdx.y * 128, n0 = blockIdx.x * 128;
  f32x4 acc[4][4];
  gemm128_mainloop(yb, wpb, m0, n0, CMODEL, sA, sB, acc);

  const int tid = threadIdx.x, w = tid >> 6, lane = tid & 63;
  const int ln = lane & 15, g = lane >> 4;
  const int wm = w >> 1, wn = w & 1;
#pragma unroll
  for (int mt = 0; mt < 4; ++mt)
#pragma unroll
    for (int nt = 0; nt < 4; ++nt){
      int o = n0 + wn*64 + nt*16 + ln;
      float bb = bp[o];
#pragma unroll
      for (int rr = 0; rr < 4; ++rr){
        int t = m0 + wm*64 + mt*16 + g*4 + rr;
        out[(size_t)t*CMODEL + o] = acc[mt][nt][rr] + bb;
      }
    }
}

// ---------------------------------------------------------------------------
extern "C" void kernel_launch(void* const* d_in, const int* in_sizes, int n_in,
                              void* d_out, int out_size, void* d_ws, size_t ws_size,
                              hipStream_t stream)
{
  const float* x  = (const float*)d_in[0];
  const float* wq = (const float*)d_in[1];
  const float* bq = (const float*)d_in[2];
  const float* wk = (const float*)d_in[3];
  const float* bk = (const float*)d_in[4];
  const float* wv = (const float*)d_in[5];
  const float* bv = (const float*)d_in[6];
  const float* wp = (const float*)d_in[7];
  const float* bp = (const float*)d_in[8];

  char* ws = (char*)d_ws;
  // workspace layout (bytes)
  u16*    xb   = (u16*)   (ws + 0);           // 8192*1024*2  = 16 MiB
  u16*    wqb  = (u16*)   (ws + 16777216);    // 2 MiB
  u16*    wkb  = (u16*)   (ws + 18874368);
  u16*    wvb  = (u16*)   (ws + 20971520);
  u16*    wpb  = (u16*)   (ws + 23068672);
  float2* rope = (float2*)(ws + 25165824);    // 2048*32*8 = 512 KiB
  u16*    Qh   = (u16*)   (ws + 25690112);    // 16 MiB  [bh][t][d]
  u16*    Kh   = (u16*)   (ws + 42467328);    // 16 MiB  [bh][t][d]
  u16*    Vt   = (u16*)   (ws + 59244544);    // 16 MiB  [bh][d][t]
  u16*    yb   = (u16*)   (ws + 76021760);    // 16 MiB  [token][C]
  // total ~88.5 MiB

  // prep: casts + rope table
  cast_bf16_kernel<<<2048, 256, 0, stream>>>(x,  xb,  MTOK*CMODEL/4);
  cast_bf16_kernel<<<1024, 256, 0, stream>>>(wq, wqb, CMODEL*CMODEL/4);
  cast_bf16_kernel<<<1024, 256, 0, stream>>>(wk, wkb, CMODEL*CMODEL/4);
  cast_bf16_kernel<<<1024, 256, 0, stream>>>(wv, wvb, CMODEL*CMODEL/4);
  cast_bf16_kernel<<<1024, 256, 0, stream>>>(wp, wpb, CMODEL*CMODEL/4);
  rope_table_kernel<<<(TSEQ*(HDIM/2) + 255)/256, 256, 0, stream>>>(rope);

  // QKV projection (+bias, +RoPE, head split, V transposed)
  gemm_qkv_kernel<<<dim3(CMODEL/128, MTOK/128, 3), 256, 0, stream>>>(
      xb, wqb, wkb, wvb, bq, bk, bv, rope, Qh, Kh, Vt);

  // causal flash attention
  attn_kernel<<<dim3(TSEQ/64, NB*NHEAD), 256, 0, stream>>>(Qh, Kh, Vt, yb);

  // output projection
  gemm_proj_kernel<<<dim3(CMODEL/128, MTOK/128), 256, 0, stream>>>(yb, wpb, bp, (float*)d_out);
}

// Round 2
// 282.641 us; speedup vs baseline: 2.3208x; 2.3208x over previous
//
#include <hip/hip_runtime.h>

typedef __attribute__((ext_vector_type(8))) __bf16 bf16x8;
typedef __attribute__((ext_vector_type(4))) float f32x4;
typedef unsigned short u16;

// Problem constants
#define TSEQ   2048
#define NB     4
#define NHEAD  16
#define HDIM   64
#define CMODEL 1024
#define MTOK   (NB*TSEQ)          // 8192 tokens

__device__ __forceinline__ u16 f2bf(float x){
  unsigned u = __float_as_uint(x);
  u += 0x7fffu + ((u >> 16) & 1u);          // RNE (no NaN inputs here)
  return (u16)(u >> 16);
}

// async global->LDS, 16B per lane. lds_base must be wave-uniform; HW writes lane i at base + i*16.
__device__ __forceinline__ void async16(const void* g, const u16* lds_base){
  __builtin_amdgcn_global_load_lds(
      (const __attribute__((address_space(1))) unsigned*)(uintptr_t)g,
      (__attribute__((address_space(3))) unsigned*)(unsigned)(uintptr_t)lds_base,
      16, 0, 0);
}

// ---------------------------------------------------------------------------
// prep kernels
// ---------------------------------------------------------------------------
__global__ void cast_bf16_kernel(const float* __restrict__ src, u16* __restrict__ dst, int n4){
  int i = blockIdx.x * blockDim.x + threadIdx.x;
  int stride = gridDim.x * blockDim.x;
  for (; i < n4; i += stride){
    float4 v = ((const float4*)src)[i];
    ((ushort4*)dst)[i] = make_ushort4(f2bf(v.x), f2bf(v.y), f2bf(v.z), f2bf(v.w));
  }
}

__global__ void rope_table_kernel(float2* __restrict__ rope){
  int i = blockIdx.x * blockDim.x + threadIdx.x;       // T * HDIM/2 = 2048*32
  if (i >= TSEQ * (HDIM/2)) return;
  int t = i >> 5, j = i & 31;
  float theta = exp2f(-(float)j * (13.287712379549449f / 32.f));
  float ang = (float)t * theta;
  rope[i] = make_float2(cosf(ang), sinf(ang));
}

// ---------------------------------------------------------------------------
// 128x128 tile GEMM mainloop, C = A(MxK) * B(NxK)^T, bf16, m97 structure.
// ---------------------------------------------------------------------------
__device__ __forceinline__ void gemm128_mainloop(
    const u16* __restrict__ A, const u16* __restrict__ B,
    int m0, int n0, int K, u16* sA, u16* sB, f32x4 acc[4][4])
{
  const int tid = threadIdx.x;
  const int w = tid >> 6, lane = tid & 63;
  const int ln = lane & 15, g = lane >> 4;
  const int wm = w >> 1, wn = w & 1;

  const f32x4 zero = {0.f, 0.f, 0.f, 0.f};
#pragma unroll
  for (int mt = 0; mt < 4; ++mt)
#pragma unroll
    for (int nt = 0; nt < 4; ++nt) acc[mt][nt] = zero;

  for (int k0 = 0; k0 < K; k0 += 32){
    __syncthreads();                       // previous tile fully consumed
#pragma unroll
    for (int i = 0; i < 2; ++i){
      int c = i*256 + tid;                 // chunk id 0..511
      int r = c >> 2, p = c & 3;
      int ks = p ^ ((r >> 1) & 3);         // pre-swizzled source k-chunk
      async16(A + (size_t)(m0 + r)*K + k0 + ks*8, sA + (size_t)(i*256 + w*64)*8);
      async16(B + (size_t)(n0 + r)*K + k0 + ks*8, sB + (size_t)(i*256 + w*64)*8);
    }
    __syncthreads();                       // drains vmcnt -> LDS ready

    bf16x8 af[4], bfr[4];
#pragma unroll
    for (int mt = 0; mt < 4; ++mt){
      int row = wm*64 + mt*16 + ln;
      int p = g ^ ((row >> 1) & 3);
      af[mt] = *(const bf16x8*)&sA[row*32 + p*8];
    }
#pragma unroll
    for (int nt = 0; nt < 4; ++nt){
      int row = wn*64 + nt*16 + ln;
      int p = g ^ ((row >> 1) & 3);
      bfr[nt] = *(const bf16x8*)&sB[row*32 + p*8];
    }
#pragma unroll
    for (int mt = 0; mt < 4; ++mt)
#pragma unroll
      for (int nt = 0; nt < 4; ++nt)
        acc[mt][nt] = __builtin_amdgcn_mfma_f32_16x16x32_bf16(af[mt], bfr[nt], acc[mt][nt], 0, 0, 0);
  }
}

// ---------------------------------------------------------------------------
// QKV projection + bias + RoPE(Q,K) + head-split; V written transposed.
// ---------------------------------------------------------------------------
__global__ __launch_bounds__(256) void gemm_qkv_kernel(
    const u16* __restrict__ xb,
    const u16* __restrict__ wqb, const u16* __restrict__ wkb, const u16* __restrict__ wvb,
    const float* __restrict__ bq, const float* __restrict__ bk, const float* __restrict__ bv,
    const float2* __restrict__ rope,
    u16* __restrict__ Qh, u16* __restrict__ Kh, u16* __restrict__ Vt)
{
  __shared__ u16 sA[128*32];
  __shared__ u16 sB[128*32];
  const int z = blockIdx.z;
  const u16*  W    = (z == 0) ? wqb : (z == 1) ? wkb : wvb;
  const float* bias = (z == 0) ? bq  : (z == 1) ? bk  : bv;
  const int m0 = blockIdx.y * 128, n0 = blockIdx.x * 128;

  f32x4 acc[4][4];
  gemm128_mainloop(xb, W, m0, n0, CMODEL, sA, sB, acc);

  const int tid = threadIdx.x, w = tid >> 6, lane = tid & 63;
  const int ln = lane & 15, g = lane >> 4;
  const int wm = w >> 1, wn = w & 1;

#pragma unroll
  for (int mt = 0; mt < 4; ++mt){
#pragma unroll
    for (int nt = 0; nt < 4; ++nt){
      int o  = n0 + wn*64 + nt*16 + ln;    // output feature 0..1023
      float bb = bias[o];
      int h  = o >> 6;
      int dd = o & 63;
      if (z < 2){
        int j = dd >> 1;
        u16* dst = (z == 0) ? Qh : Kh;
#pragma unroll
        for (int rr = 0; rr < 4; ++rr){
          int t  = m0 + wm*64 + mt*16 + g*4 + rr;   // global token
          int b  = t >> 11, tt = t & (TSEQ-1);
          float v  = acc[mt][nt][rr] + bb;
          float pv = __shfl_xor(v, 1);              // rope partner (o^1), same row
          float2 cs = rope[tt*32 + j];
          float out = ((o & 1) == 0) ? (v*cs.x - pv*cs.y) : (pv*cs.y + v*cs.x);
          dst[(size_t)((b*NHEAD + h)*TSEQ + tt)*HDIM + dd] = f2bf(out);
        }
      } else {
        int t0 = m0 + wm*64 + mt*16 + g*4;
        int b  = t0 >> 11, tt0 = t0 & (TSEQ-1);
        u16 pk[4];
#pragma unroll
        for (int rr = 0; rr < 4; ++rr) pk[rr] = f2bf(acc[mt][nt][rr] + bb);
        *(ushort4*)&Vt[(size_t)((b*NHEAD + h)*HDIM + dd)*TSEQ + tt0] =
            make_ushort4(pk[0], pk[1], pk[2], pk[3]);
      }
    }
  }
}

// ---------------------------------------------------------------------------
// Flash attention v2, causal.
//  - K,V tiles staged ONCE per block into LDS (shared by 4 waves),
//    double-buffered, global_load_lds w/ pre-swizzled source (chunk p^(r&7))
//    so ds_read_b128 hits all 8 bank-groups evenly.
//  - Software pipeline: stage jt+1 right after the barrier, compute jt.
//  - Work balance: block handles q-tiles p and 31-p (33 kv-tiles constant).
//  - XCD remap: all 16 blocks of one (b,h) land on one XCD's L2.
// ---------------------------------------------------------------------------
__global__ __launch_bounds__(256) void attn_kernel(
    const u16* __restrict__ Qh, const u16* __restrict__ Kh,
    const u16* __restrict__ Vt, u16* __restrict__ yb)
{
  __shared__ u16 sK[2][64*64];
  __shared__ u16 sV[2][64*64];
  __shared__ u16 plds[4][16*64];

  const int tid = threadIdx.x, w = tid >> 6, lane = tid & 63;
  const int ln = lane & 15, g = lane >> 4;

  // XCD-aware remap of the 1024-block 1D grid: bid&7 = XCD slot.
  const int bid = blockIdx.x;
  const int xcd = bid & 7, s = bid >> 3;          // s: 0..127
  const int p   = s & 15;                          // pair index 0..15
  const int bh  = xcd * 8 + (s >> 4);              // 8 bh per XCD slot
  const int b   = bh >> 4, h = bh & (NHEAD-1);

  const u16* Qbase = Qh + (size_t)bh * TSEQ * HDIM;
  const u16* Kbase = Kh + (size_t)bh * TSEQ * HDIM;
  const u16* Vbase = Vt + (size_t)bh * HDIM * TSEQ;
  u16* pw = plds[w];

  const f32x4 zero = {0.f, 0.f, 0.f, 0.f};
  const float SC = 0.125f * 1.44269504f;   // 1/sqrt(64) * log2(e)

  int buf = 0;
#pragma unroll 1
  for (int pi = 0; pi < 2; ++pi){
    const int qt = pi ? (31 - p) : p;      // q-tile index, 64 rows
    const int qb = qt*64 + w*16;

    bf16x8 aq[2];
#pragma unroll
    for (int kc = 0; kc < 2; ++kc)
      aq[kc] = *(const bf16x8*)&Qbase[(size_t)(qb + ln)*HDIM + kc*32 + g*8];

    f32x4 yacc[4];
#pragma unroll
    for (int dt = 0; dt < 4; ++dt) yacc[dt] = zero;
    float m2[4], l2[4];
#pragma unroll
    for (int rr = 0; rr < 4; ++rr){ m2[rr] = -1e30f; l2[rr] = 0.f; }

    // stage tile 0 of this pass
    {
      u16* sKb = sK[buf]; u16* sVb = sV[buf];
#pragma unroll
      for (int i = 0; i < 2; ++i){
        int c = i*256 + tid, r = c >> 3, pc = c & 7;
        async16(Kbase + (size_t)r*HDIM + ((pc ^ (r&7))<<3), sKb + (size_t)(i*256 + w*64)*8);
        async16(Vbase + (size_t)r*TSEQ + ((pc ^ (r&7))<<3), sVb + (size_t)(i*256 + w*64)*8);
      }
    }

#pragma unroll 1
    for (int jt = 0; jt <= qt; ++jt){
      __syncthreads();                     // drains staged loads; all waves synced
      if (jt < qt){                        // prefetch next tile into other buffer
        u16* sKb = sK[buf^1]; u16* sVb = sV[buf^1];
#pragma unroll
        for (int i = 0; i < 2; ++i){
          int c = i*256 + tid, r = c >> 3, pc = c & 7;
          async16(Kbase + (size_t)((jt+1)*64 + r)*HDIM + ((pc ^ (r&7))<<3), sKb + (size_t)(i*256 + w*64)*8);
          async16(Vbase + (size_t)r*TSEQ + (jt+1)*64 + ((pc ^ (r&7))<<3),   sVb + (size_t)(i*256 + w*64)*8);
        }
      }
      const u16* sKb = sK[buf];
      const u16* sVb = sV[buf];

      // S = Q K^T for this 64-wide kv tile
      f32x4 sc4[4];
#pragma unroll
      for (int nt = 0; nt < 4; ++nt){
        int row = nt*16 + ln;
        const u16* base = &sKb[row*64];
        bf16x8 k0 = *(const bf16x8*)&base[((g     ^ (row&7))<<3)];
        bf16x8 k1 = *(const bf16x8*)&base[(((4+g) ^ (row&7))<<3)];
        f32x4 t = __builtin_amdgcn_mfma_f32_16x16x32_bf16(aq[0], k0, zero, 0, 0, 0);
        sc4[nt]  = __builtin_amdgcn_mfma_f32_16x16x32_bf16(aq[1], k1, t,    0, 0, 0);
      }
      // scale + causal mask (only diagonal tile)
#pragma unroll
      for (int nt = 0; nt < 4; ++nt)
#pragma unroll
        for (int rr = 0; rr < 4; ++rr){
          float v = sc4[nt][rr] * SC;
          if (jt == qt){
            int tk = jt*64 + nt*16 + ln;
            int tq = qb + g*4 + rr;
            if (tk > tq) v = -1e30f;
          }
          sc4[nt][rr] = v;
        }
      // wave-parallel row max (reduce over ln within each g-group)
      float tm[4];
#pragma unroll
      for (int rr = 0; rr < 4; ++rr)
        tm[rr] = fmaxf(fmaxf(sc4[0][rr], sc4[1][rr]), fmaxf(sc4[2][rr], sc4[3][rr]));
#pragma unroll
      for (int mk = 1; mk <= 8; mk <<= 1)
#pragma unroll
        for (int rr = 0; rr < 4; ++rr) tm[rr] = fmaxf(tm[rr], __shfl_xor(tm[rr], mk));

      float scl[4], ts[4];
#pragma unroll
      for (int rr = 0; rr < 4; ++rr){
        float mn = fmaxf(m2[rr], tm[rr]);
        scl[rr] = exp2f(m2[rr] - mn);
        m2[rr] = mn;
        ts[rr] = 0.f;
      }
#pragma unroll
      for (int nt = 0; nt < 4; ++nt)
#pragma unroll
        for (int rr = 0; rr < 4; ++rr){
          float pv = exp2f(sc4[nt][rr] - m2[rr]);
          sc4[nt][rr] = pv;
          ts[rr] += pv;
        }
#pragma unroll
      for (int mk = 1; mk <= 8; mk <<= 1)
#pragma unroll
        for (int rr = 0; rr < 4; ++rr) ts[rr] += __shfl_xor(ts[rr], mk);
#pragma unroll
      for (int rr = 0; rr < 4; ++rr) l2[rr] = l2[rr]*scl[rr] + ts[rr];
#pragma unroll
      for (int dt = 0; dt < 4; ++dt)
#pragma unroll
        for (int rr = 0; rr < 4; ++rr) yacc[dt][rr] *= scl[rr];

      // P -> per-wave LDS (XOR-swizzled), then PV
#pragma unroll
      for (int nt = 0; nt < 4; ++nt)
#pragma unroll
        for (int rr = 0; rr < 4; ++rr){
          int row = g*4 + rr;
          int ec  = (nt*16 + ln) ^ ((row & 7) << 3);
          pw[row*64 + ec] = f2bf(sc4[nt][rr]);
        }
#pragma unroll
      for (int kc = 0; kc < 2; ++kc){
        int colbase = (kc*32 + g*8) ^ ((ln & 7) << 3);
        bf16x8 ap = *(const bf16x8*)&pw[ln*64 + colbase];
#pragma unroll
        for (int dt = 0; dt < 4; ++dt){
          int row = dt*16 + ln;
          bf16x8 bv = *(const bf16x8*)&sVb[row*64 + (((kc*4+g) ^ (row&7))<<3)];
          yacc[dt] = __builtin_amdgcn_mfma_f32_16x16x32_bf16(ap, bv, yacc[dt], 0, 0, 0);
        }
      }
      buf ^= 1;
    }

    // epilogue: divide by l, write [token][C] bf16 for the output projection
    float inv[4];
#pragma unroll
    for (int rr = 0; rr < 4; ++rr) inv[rr] = 1.0f / l2[rr];
#pragma unroll
    for (int dt = 0; dt < 4; ++dt)
#pragma unroll
      for (int rr = 0; rr < 4; ++rr){
        int tt = qb + g*4 + rr;
        int c  = h*HDIM + dt*16 + ln;
        yb[(size_t)(b*TSEQ + tt)*CMODEL + c] = f2bf(yacc[dt][rr] * inv[rr]);
      }
  }
}

// ---------------------------------------------------------------------------
// output projection, f32 result straight to d_out
// ---------------------------------------------------------------------------
__global__ __launch_bounds__(256) void gemm_proj_kernel(
    const u16* __restrict__ yb, const u16* __restrict__ wpb,
    const float* __restrict__ bp, float* __restrict__ out)
{
  __shared__ u16 sA[128*32];
  __shared__ u16 sB[128*32];
  const int m0 = blockIdx.y * 128, n0 = blockIdx.x * 128;
  f32x4 acc[4][4];
  gemm128_mainloop(yb, wpb, m0, n0, CMODEL, sA, sB, acc);

  const int tid = threadIdx.x, w = tid >> 6, lane = tid & 63;
  const int ln = lane & 15, g = lane >> 4;
  const int wm = w >> 1, wn = w & 1;
#pragma unroll
  for (int mt = 0; mt < 4; ++mt)
#pragma unroll
    for (int nt = 0; nt < 4; ++nt){
      int o = n0 + wn*64 + nt*16 + ln;
      float bb = bp[o];
#pragma unroll
      for (int rr = 0; rr < 4; ++rr){
        int t = m0 + wm*64 + mt*16 + g*4 + rr;
        out[(size_t)t*CMODEL + o] = acc[mt][nt][rr] + bb;
      }
    }
}

// ---------------------------------------------------------------------------
extern "C" void kernel_launch(void* const* d_in, const int* in_sizes, int n_in,
                              void* d_out, int out_size, void* d_ws, size_t ws_size,
                              hipStream_t stream)
{
  const float* x  = (const float*)d_in[0];
  const float* wq = (const float*)d_in[1];
  const float* bq = (const float*)d_in[2];
  const float* wk = (const float*)d_in[3];
  const float* bk = (const float*)d_in[4];
  const float* wv = (const float*)d_in[5];
  const float* bv = (const float*)d_in[6];
  const float* wp = (const float*)d_in[7];
  const float* bp = (const float*)d_in[8];

  char* ws = (char*)d_ws;
  u16*    xb   = (u16*)   (ws + 0);           // 16 MiB
  u16*    wqb  = (u16*)   (ws + 16777216);    // 2 MiB
  u16*    wkb  = (u16*)   (ws + 18874368);
  u16*    wvb  = (u16*)   (ws + 20971520);
  u16*    wpb  = (u16*)   (ws + 23068672);
  float2* rope = (float2*)(ws + 25165824);    // 512 KiB
  u16*    Qh   = (u16*)   (ws + 25690112);    // 16 MiB  [bh][t][d]
  u16*    Kh   = (u16*)   (ws + 42467328);    // 16 MiB  [bh][t][d]
  u16*    Vt   = (u16*)   (ws + 59244544);    // 16 MiB  [bh][d][t]
  u16*    yb   = (u16*)   (ws + 76021760);    // 16 MiB  [token][C]

  cast_bf16_kernel<<<2048, 256, 0, stream>>>(x,  xb,  MTOK*CMODEL/4);
  cast_bf16_kernel<<<1024, 256, 0, stream>>>(wq, wqb, CMODEL*CMODEL/4);
  cast_bf16_kernel<<<1024, 256, 0, stream>>>(wk, wkb, CMODEL*CMODEL/4);
  cast_bf16_kernel<<<1024, 256, 0, stream>>>(wv, wvb, CMODEL*CMODEL/4);
  cast_bf16_kernel<<<1024, 256, 0, stream>>>(wp, wpb, CMODEL*CMODEL/4);
  rope_table_kernel<<<(TSEQ*(HDIM/2) + 255)/256, 256, 0, stream>>>(rope);

  gemm_qkv_kernel<<<dim3(CMODEL/128, MTOK/128, 3), 256, 0, stream>>>(
      xb, wqb, wkb, wvb, bq, bk, bv, rope, Qh, Kh, Vt);

  attn_kernel<<<dim3(1024), 256, 0, stream>>>(Qh, Kh, Vt, yb);

  gemm_proj_kernel<<<dim3(CMODEL/128, MTOK/128), 256, 0, stream>>>(yb, wpb, bp, (float*)d_out);
}

// Round 3
// 250.388 us; speedup vs baseline: 2.6198x; 1.1288x over previous
//
#include <hip/hip_runtime.h>

typedef __attribute__((ext_vector_type(8))) __bf16 bf16x8;
typedef __attribute__((ext_vector_type(4))) float f32x4;
typedef unsigned short u16;

// Problem constants
#define TSEQ   2048
#define NB     4
#define NHEAD  16
#define HDIM   64
#define CMODEL 1024
#define MTOK   (NB*TSEQ)          // 8192 tokens

__device__ __forceinline__ u16 f2bf(float x){
  unsigned u = __float_as_uint(x);
  u += 0x7fffu + ((u >> 16) & 1u);          // RNE (no NaN inputs here)
  return (u16)(u >> 16);
}

// async global->LDS, 16B per lane. lds_base must be wave-uniform; HW writes lane i at base + i*16.
__device__ __forceinline__ void async16(const void* g, const u16* lds_base){
  __builtin_amdgcn_global_load_lds(
      (const __attribute__((address_space(1))) unsigned*)(uintptr_t)g,
      (__attribute__((address_space(3))) unsigned*)(unsigned)(uintptr_t)lds_base,
      16, 0, 0);
}

// ---------------------------------------------------------------------------
// prep kernels
// ---------------------------------------------------------------------------
__global__ void cast_bf16_kernel(const float* __restrict__ src, u16* __restrict__ dst, int n4){
  int i = blockIdx.x * blockDim.x + threadIdx.x;
  int stride = gridDim.x * blockDim.x;
  for (; i < n4; i += stride){
    float4 v = ((const float4*)src)[i];
    ((ushort4*)dst)[i] = make_ushort4(f2bf(v.x), f2bf(v.y), f2bf(v.z), f2bf(v.w));
  }
}

__global__ void rope_table_kernel(float2* __restrict__ rope){
  int i = blockIdx.x * blockDim.x + threadIdx.x;       // T * HDIM/2 = 2048*32
  if (i >= TSEQ * (HDIM/2)) return;
  int t = i >> 5, j = i & 31;
  float theta = exp2f(-(float)j * (13.287712379549449f / 32.f));
  float ang = (float)t * theta;
  rope[i] = make_float2(cosf(ang), sinf(ang));
}

// ---------------------------------------------------------------------------
// 128x128 tile GEMM mainloop, C = A(MxK) * B(NxK)^T, bf16, m97 structure.
// ---------------------------------------------------------------------------
__device__ __forceinline__ void gemm128_mainloop(
    const u16* __restrict__ A, const u16* __restrict__ B,
    int m0, int n0, int K, u16* sA, u16* sB, f32x4 acc[4][4])
{
  const int tid = threadIdx.x;
  const int w = tid >> 6, lane = tid & 63;
  const int ln = lane & 15, g = lane >> 4;
  const int wm = w >> 1, wn = w & 1;

  const f32x4 zero = {0.f, 0.f, 0.f, 0.f};
#pragma unroll
  for (int mt = 0; mt < 4; ++mt)
#pragma unroll
    for (int nt = 0; nt < 4; ++nt) acc[mt][nt] = zero;

  for (int k0 = 0; k0 < K; k0 += 32){
    __syncthreads();                       // previous tile fully consumed
#pragma unroll
    for (int i = 0; i < 2; ++i){
      int c = i*256 + tid;                 // chunk id 0..511
      int r = c >> 2, p = c & 3;
      int ks = p ^ ((r >> 1) & 3);         // pre-swizzled source k-chunk
      async16(A + (size_t)(m0 + r)*K + k0 + ks*8, sA + (size_t)(i*256 + w*64)*8);
      async16(B + (size_t)(n0 + r)*K + k0 + ks*8, sB + (size_t)(i*256 + w*64)*8);
    }
    __syncthreads();                       // drains vmcnt -> LDS ready

    bf16x8 af[4], bfr[4];
#pragma unroll
    for (int mt = 0; mt < 4; ++mt){
      int row = wm*64 + mt*16 + ln;
      int p = g ^ ((row >> 1) & 3);
      af[mt] = *(const bf16x8*)&sA[row*32 + p*8];
    }
#pragma unroll
    for (int nt = 0; nt < 4; ++nt){
      int row = wn*64 + nt*16 + ln;
      int p = g ^ ((row >> 1) & 3);
      bfr[nt] = *(const bf16x8*)&sB[row*32 + p*8];
    }
#pragma unroll
    for (int mt = 0; mt < 4; ++mt)
#pragma unroll
      for (int nt = 0; nt < 4; ++nt)
        acc[mt][nt] = __builtin_amdgcn_mfma_f32_16x16x32_bf16(af[mt], bfr[nt], acc[mt][nt], 0, 0, 0);
  }
}

// ---------------------------------------------------------------------------
// QKV projection + bias + RoPE(Q,K) + head-split; V written transposed.
// Q is pre-scaled by log2(e)/sqrt(d) so attention needs no per-tile scaling.
// ---------------------------------------------------------------------------
#define SCQ 0.18033688011112042f   // 0.125 * log2(e)

__global__ __launch_bounds__(256) void gemm_qkv_kernel(
    const u16* __restrict__ xb,
    const u16* __restrict__ wqb, const u16* __restrict__ wkb, const u16* __restrict__ wvb,
    const float* __restrict__ bq, const float* __restrict__ bk, const float* __restrict__ bv,
    const float2* __restrict__ rope,
    u16* __restrict__ Qh, u16* __restrict__ Kh, u16* __restrict__ Vt)
{
  __shared__ u16 sA[128*32];
  __shared__ u16 sB[128*32];
  const int z = blockIdx.z;
  const u16*  W    = (z == 0) ? wqb : (z == 1) ? wkb : wvb;
  const float* bias = (z == 0) ? bq  : (z == 1) ? bk  : bv;
  const int m0 = blockIdx.y * 128, n0 = blockIdx.x * 128;

  f32x4 acc[4][4];
  gemm128_mainloop(xb, W, m0, n0, CMODEL, sA, sB, acc);

  const int tid = threadIdx.x, w = tid >> 6, lane = tid & 63;
  const int ln = lane & 15, g = lane >> 4;
  const int wm = w >> 1, wn = w & 1;

#pragma unroll
  for (int mt = 0; mt < 4; ++mt){
#pragma unroll
    for (int nt = 0; nt < 4; ++nt){
      int o  = n0 + wn*64 + nt*16 + ln;    // output feature 0..1023
      float bb = bias[o];
      int h  = o >> 6;
      int dd = o & 63;
      if (z < 2){
        int j = dd >> 1;
        u16* dst = (z == 0) ? Qh : Kh;
        float qs = (z == 0) ? SCQ : 1.0f;
#pragma unroll
        for (int rr = 0; rr < 4; ++rr){
          int t  = m0 + wm*64 + mt*16 + g*4 + rr;   // global token
          int b  = t >> 11, tt = t & (TSEQ-1);
          float v  = acc[mt][nt][rr] + bb;
          float pv = __shfl_xor(v, 1);              // rope partner (o^1), same row
          float2 cs = rope[tt*32 + j];
          float out = ((o & 1) == 0) ? (v*cs.x - pv*cs.y) : (pv*cs.y + v*cs.x);
          dst[(size_t)((b*NHEAD + h)*TSEQ + tt)*HDIM + dd] = f2bf(out * qs);
        }
      } else {
        int t0 = m0 + wm*64 + mt*16 + g*4;
        int b  = t0 >> 11, tt0 = t0 & (TSEQ-1);
        u16 pk[4];
#pragma unroll
        for (int rr = 0; rr < 4; ++rr) pk[rr] = f2bf(acc[mt][nt][rr] + bb);
        *(ushort4*)&Vt[(size_t)((b*NHEAD + h)*HDIM + dd)*TSEQ + tt0] =
            make_ushort4(pk[0], pk[1], pk[2], pk[3]);
      }
    }
  }
}

// ---------------------------------------------------------------------------
// Flash attention v3, causal. Structure as v2 (LDS-shared K/V, double-buffered,
// paired q-tiles, XCD remap) with the VALU diet:
//  - Q pre-scaled (no per-tile scale mul); mask only on the diagonal tile.
//  - defer-max (THR=8 in log2 units): rescale only when the row max grows.
//  - per-lane partial row sums; single shuffle-tree at epilogue.
//  - truncating bf16 pack for P (1 VALU op/elem).
// ---------------------------------------------------------------------------
__global__ __launch_bounds__(256) void attn_kernel(
    const u16* __restrict__ Qh, const u16* __restrict__ Kh,
    const u16* __restrict__ Vt, u16* __restrict__ yb)
{
  __shared__ u16 sK[2][64*64];
  __shared__ u16 sV[2][64*64];
  __shared__ u16 plds[4][16*64];

  const int tid = threadIdx.x, w = tid >> 6, lane = tid & 63;
  const int ln = lane & 15, g = lane >> 4;

  // XCD-aware remap of the 1024-block 1D grid: bid&7 = XCD slot.
  const int bid = blockIdx.x;
  const int xcd = bid & 7, s = bid >> 3;          // s: 0..127
  const int p   = s & 15;                          // pair index 0..15
  const int bh  = xcd * 8 + (s >> 4);              // 8 bh per XCD slot
  const int b   = bh >> 4, h = bh & (NHEAD-1);

  const u16* Qbase = Qh + (size_t)bh * TSEQ * HDIM;
  const u16* Kbase = Kh + (size_t)bh * TSEQ * HDIM;
  const u16* Vbase = Vt + (size_t)bh * HDIM * TSEQ;
  u16* pw = plds[w];

  const f32x4 zero = {0.f, 0.f, 0.f, 0.f};

  int buf = 0;
#pragma unroll 1
  for (int pi = 0; pi < 2; ++pi){
    const int qt = pi ? (31 - p) : p;      // q-tile index, 64 rows
    const int qb = qt*64 + w*16;

    bf16x8 aq[2];
#pragma unroll
    for (int kc = 0; kc < 2; ++kc)
      aq[kc] = *(const bf16x8*)&Qbase[(size_t)(qb + ln)*HDIM + kc*32 + g*8];

    f32x4 yacc[4];
#pragma unroll
    for (int dt = 0; dt < 4; ++dt) yacc[dt] = zero;
    float m2[4], lp[4];
#pragma unroll
    for (int rr = 0; rr < 4; ++rr){ m2[rr] = -1e30f; lp[rr] = 0.f; }

    // stage tile 0 of this pass
    {
      u16* sKb = sK[buf]; u16* sVb = sV[buf];
#pragma unroll
      for (int i = 0; i < 2; ++i){
        int c = i*256 + tid, r = c >> 3, pc = c & 7;
        async16(Kbase + (size_t)r*HDIM + ((pc ^ (r&7))<<3), sKb + (size_t)(i*256 + w*64)*8);
        async16(Vbase + (size_t)r*TSEQ + ((pc ^ (r&7))<<3), sVb + (size_t)(i*256 + w*64)*8);
      }
    }

#pragma unroll 1
    for (int jt = 0; jt <= qt; ++jt){
      __syncthreads();                     // drains staged loads; all waves synced
      if (jt < qt){                        // prefetch next tile into other buffer
        u16* sKb = sK[buf^1]; u16* sVb = sV[buf^1];
#pragma unroll
        for (int i = 0; i < 2; ++i){
          int c = i*256 + tid, r = c >> 3, pc = c & 7;
          async16(Kbase + (size_t)((jt+1)*64 + r)*HDIM + ((pc ^ (r&7))<<3), sKb + (size_t)(i*256 + w*64)*8);
          async16(Vbase + (size_t)r*TSEQ + (jt+1)*64 + ((pc ^ (r&7))<<3),   sVb + (size_t)(i*256 + w*64)*8);
        }
      }
      const u16* sKb = sK[buf];
      const u16* sVb = sV[buf];

      // S = Q K^T for this 64-wide kv tile (Q pre-scaled; log2 domain)
      f32x4 sc4[4];
#pragma unroll
      for (int nt = 0; nt < 4; ++nt){
        int row = nt*16 + ln;
        const u16* base = &sKb[row*64];
        bf16x8 k0 = *(const bf16x8*)&base[((g     ^ (row&7))<<3)];
        bf16x8 k1 = *(const bf16x8*)&base[(((4+g) ^ (row&7))<<3)];
        f32x4 t = __builtin_amdgcn_mfma_f32_16x16x32_bf16(aq[0], k0, zero, 0, 0, 0);
        sc4[nt]  = __builtin_amdgcn_mfma_f32_16x16x32_bf16(aq[1], k1, t,    0, 0, 0);
      }
      // causal mask — diagonal tile only (wave-uniform branch)
      if (jt == qt){
#pragma unroll
        for (int nt = 0; nt < 4; ++nt){
          int tk = nt*16 + ln;             // relative to tile; tq relative = w*16+g*4+rr... both +jt*64
#pragma unroll
          for (int rr = 0; rr < 4; ++rr){
            int tq = w*16 + g*4 + rr - (qt - jt)*0;  // same tile: compare within
            // absolute: tk_abs = jt*64+tk, tq_abs = qb+g*4+rr = jt*64 + w*16+g*4+rr
            if (tk > w*16 + g*4 + rr) sc4[nt][rr] = -1e30f;
            (void)tq;
          }
        }
      }
      // wave-parallel row max
      float tm[4];
#pragma unroll
      for (int rr = 0; rr < 4; ++rr)
        tm[rr] = fmaxf(fmaxf(sc4[0][rr], sc4[1][rr]), fmaxf(sc4[2][rr], sc4[3][rr]));
#pragma unroll
      for (int mk = 1; mk <= 8; mk <<= 1)
#pragma unroll
        for (int rr = 0; rr < 4; ++rr) tm[rr] = fmaxf(tm[rr], __shfl_xor(tm[rr], mk));

      // defer-max: rescale only if some row max grew by more than 8 (log2)
      float growth = fmaxf(fmaxf(tm[0]-m2[0], tm[1]-m2[1]), fmaxf(tm[2]-m2[2], tm[3]-m2[3]));
      if (__any(growth > 8.0f)){
#pragma unroll
        for (int rr = 0; rr < 4; ++rr){
          float mn  = fmaxf(m2[rr], tm[rr]);
          float scl = exp2f(m2[rr] - mn);
          m2[rr] = mn;
          lp[rr] *= scl;
          yacc[0][rr] *= scl; yacc[1][rr] *= scl; yacc[2][rr] *= scl; yacc[3][rr] *= scl;
        }
      }

      // exp + per-lane partial sum + truncating pack -> per-wave LDS (XOR-swizzled)
      float ts[4] = {0.f, 0.f, 0.f, 0.f};
#pragma unroll
      for (int nt = 0; nt < 4; ++nt)
#pragma unroll
        for (int rr = 0; rr < 4; ++rr){
          float pv = exp2f(sc4[nt][rr] - m2[rr]);
          ts[rr] += pv;
          int row = g*4 + rr;
          int ec  = (nt*16 + ln) ^ ((row & 7) << 3);
          pw[row*64 + ec] = (u16)(__float_as_uint(pv) >> 16);
        }
#pragma unroll
      for (int rr = 0; rr < 4; ++rr) lp[rr] += ts[rr];

      // PV
#pragma unroll
      for (int kc = 0; kc < 2; ++kc){
        int colbase = (kc*32 + g*8) ^ ((ln & 7) << 3);
        bf16x8 ap = *(const bf16x8*)&pw[ln*64 + colbase];
#pragma unroll
        for (int dt = 0; dt < 4; ++dt){
          int row = dt*16 + ln;
          bf16x8 bv = *(const bf16x8*)&sVb[row*64 + (((kc*4+g) ^ (row&7))<<3)];
          yacc[dt] = __builtin_amdgcn_mfma_f32_16x16x32_bf16(ap, bv, yacc[dt], 0, 0, 0);
        }
      }
      buf ^= 1;
    }

    // epilogue: reduce row sums across the 16 lanes, divide, write bf16
#pragma unroll
    for (int mk = 1; mk <= 8; mk <<= 1)
#pragma unroll
      for (int rr = 0; rr < 4; ++rr) lp[rr] += __shfl_xor(lp[rr], mk);
    float inv[4];
#pragma unroll
    for (int rr = 0; rr < 4; ++rr) inv[rr] = 1.0f / lp[rr];
#pragma unroll
    for (int dt = 0; dt < 4; ++dt)
#pragma unroll
      for (int rr = 0; rr < 4; ++rr){
        int tt = qb + g*4 + rr;
        int c  = h*HDIM + dt*16 + ln;
        yb[(size_t)(b*TSEQ + tt)*CMODEL + c] = f2bf(yacc[dt][rr] * inv[rr]);
      }

    // reset lp for next pass handled by re-init at top of pi loop
  }
}

// ---------------------------------------------------------------------------
// output projection, f32 result straight to d_out
// ---------------------------------------------------------------------------
__global__ __launch_bounds__(256) void gemm_proj_kernel(
    const u16* __restrict__ yb, const u16* __restrict__ wpb,
    const float* __restrict__ bp, float* __restrict__ out)
{
  __shared__ u16 sA[128*32];
  __shared__ u16 sB[128*32];
  const int m0 = blockIdx.y * 128, n0 = blockIdx.x * 128;
  f32x4 acc[4][4];
  gemm128_mainloop(yb, wpb, m0, n0, CMODEL, sA, sB, acc);

  const int tid = threadIdx.x, w = tid >> 6, lane = tid & 63;
  const int ln = lane & 15, g = lane >> 4;
  const int wm = w >> 1, wn = w & 1;
#pragma unroll
  for (int mt = 0; mt < 4; ++mt)
#pragma unroll
    for (int nt = 0; nt < 4; ++nt){
      int o = n0 + wn*64 + nt*16 + ln;
      float bb = bp[o];
#pragma unroll
      for (int rr = 0; rr < 4; ++rr){
        int t = m0 + wm*64 + mt*16 + g*4 + rr;
        out[(size_t)t*CMODEL + o] = acc[mt][nt][rr] + bb;
      }
    }
}

// ---------------------------------------------------------------------------
extern "C" void kernel_launch(void* const* d_in, const int* in_sizes, int n_in,
                              void* d_out, int out_size, void* d_ws, size_t ws_size,
                              hipStream_t stream)
{
  const float* x  = (const float*)d_in[0];
  const float* wq = (const float*)d_in[1];
  const float* bq = (const float*)d_in[2];
  const float* wk = (const float*)d_in[3];
  const float* bk = (const float*)d_in[4];
  const float* wv = (const float*)d_in[5];
  const float* bv = (const float*)d_in[6];
  const float* wp = (const float*)d_in[7];
  const float* bp = (const float*)d_in[8];

  char* ws = (char*)d_ws;
  u16*    xb   = (u16*)   (ws + 0);           // 16 MiB
  u16*    wqb  = (u16*)   (ws + 16777216);    // 2 MiB
  u16*    wkb  = (u16*)   (ws + 18874368);
  u16*    wvb  = (u16*)   (ws + 20971520);
  u16*    wpb  = (u16*)   (ws + 23068672);
  float2* rope = (float2*)(ws + 25165824);    // 512 KiB
  u16*    Qh   = (u16*)   (ws + 25690112);    // 16 MiB  [bh][t][d]
  u16*    Kh   = (u16*)   (ws + 42467328);    // 16 MiB  [bh][t][d]
  u16*    Vt   = (u16*)   (ws + 59244544);    // 16 MiB  [bh][d][t]
  u16*    yb   = (u16*)   (ws + 76021760);    // 16 MiB  [token][C]

  cast_bf16_kernel<<<2048, 256, 0, stream>>>(x,  xb,  MTOK*CMODEL/4);
  cast_bf16_kernel<<<1024, 256, 0, stream>>>(wq, wqb, CMODEL*CMODEL/4);
  cast_bf16_kernel<<<1024, 256, 0, stream>>>(wk, wkb, CMODEL*CMODEL/4);
  cast_bf16_kernel<<<1024, 256, 0, stream>>>(wv, wvb, CMODEL*CMODEL/4);
  cast_bf16_kernel<<<1024, 256, 0, stream>>>(wp, wpb, CMODEL*CMODEL/4);
  rope_table_kernel<<<(TSEQ*(HDIM/2) + 255)/256, 256, 0, stream>>>(rope);

  gemm_qkv_kernel<<<dim3(CMODEL/128, MTOK/128, 3), 256, 0, stream>>>(
      xb, wqb, wkb, wvb, bq, bk, bv, rope, Qh, Kh, Vt);

  attn_kernel<<<dim3(1024), 256, 0, stream>>>(Qh, Kh, Vt, yb);

  gemm_proj_kernel<<<dim3(CMODEL/128, MTOK/128), 256, 0, stream>>>(yb, wpb, bp, (float*)d_out);
}

// Round 4
// 228.366 us; speedup vs baseline: 2.8724x; 1.0964x over previous
//
#include <hip/hip_runtime.h>

typedef __attribute__((ext_vector_type(8))) __bf16 bf16x8;
typedef __attribute__((ext_vector_type(4))) float f32x4;
typedef unsigned short u16;

// Problem constants
#define TSEQ   2048
#define NB     4
#define NHEAD  16
#define HDIM   64
#define CMODEL 1024
#define MTOK   (NB*TSEQ)          // 8192 tokens

__device__ __forceinline__ u16 f2bf(float x){
  unsigned u = __float_as_uint(x);
  u += 0x7fffu + ((u >> 16) & 1u);          // RNE (no NaN inputs here)
  return (u16)(u >> 16);
}

// async global->LDS, 16B per lane. lds_base must be wave-uniform; HW writes lane i at base + i*16.
__device__ __forceinline__ void async16(const void* g, const u16* lds_base){
  __builtin_amdgcn_global_load_lds(
      (const __attribute__((address_space(1))) unsigned*)(uintptr_t)g,
      (__attribute__((address_space(3))) unsigned*)(unsigned)(uintptr_t)lds_base,
      16, 0, 0);
}

// ---------------------------------------------------------------------------
// prep kernels
// ---------------------------------------------------------------------------
__global__ void cast_bf16_kernel(const float* __restrict__ src, u16* __restrict__ dst, int n4){
  int i = blockIdx.x * blockDim.x + threadIdx.x;
  int stride = gridDim.x * blockDim.x;
  for (; i < n4; i += stride){
    float4 v = ((const float4*)src)[i];
    ((ushort4*)dst)[i] = make_ushort4(f2bf(v.x), f2bf(v.y), f2bf(v.z), f2bf(v.w));
  }
}

// 4 weight matrices in one launch (blockIdx.y selects)
__global__ void cast4_bf16_kernel(const float* __restrict__ s0, const float* __restrict__ s1,
                                  const float* __restrict__ s2, const float* __restrict__ s3,
                                  u16* __restrict__ d0, u16* __restrict__ d1,
                                  u16* __restrict__ d2, u16* __restrict__ d3, int n4){
  int which = blockIdx.y;
  const float* s = (which==0)?s0:(which==1)?s1:(which==2)?s2:s3;
  u16* d        = (which==0)?d0:(which==1)?d1:(which==2)?d2:d3;
  int i = blockIdx.x * blockDim.x + threadIdx.x;
  int stride = gridDim.x * blockDim.x;
  for (; i < n4; i += stride){
    float4 v = ((const float4*)s)[i];
    ((ushort4*)d)[i] = make_ushort4(f2bf(v.x), f2bf(v.y), f2bf(v.z), f2bf(v.w));
  }
}

__global__ void rope_table_kernel(float2* __restrict__ rope){
  int i = blockIdx.x * blockDim.x + threadIdx.x;       // T * HDIM/2 = 2048*32
  if (i >= TSEQ * (HDIM/2)) return;
  int t = i >> 5, j = i & 31;
  float theta = exp2f(-(float)j * (13.287712379549449f / 32.f));
  float ang = (float)t * theta;
  rope[i] = make_float2(cosf(ang), sinf(ang));
}

// ---------------------------------------------------------------------------
// 128x128 tile GEMM mainloop, C = A(MxK) * B(NxK)^T, bf16, m97 structure.
// ---------------------------------------------------------------------------
__device__ __forceinline__ void gemm128_mainloop(
    const u16* __restrict__ A, const u16* __restrict__ B,
    int m0, int n0, int K, u16* sA, u16* sB, f32x4 acc[4][4])
{
  const int tid = threadIdx.x;
  const int w = tid >> 6, lane = tid & 63;
  const int ln = lane & 15, g = lane >> 4;
  const int wm = w >> 1, wn = w & 1;

  const f32x4 zero = {0.f, 0.f, 0.f, 0.f};
#pragma unroll
  for (int mt = 0; mt < 4; ++mt)
#pragma unroll
    for (int nt = 0; nt < 4; ++nt) acc[mt][nt] = zero;

  for (int k0 = 0; k0 < K; k0 += 32){
    __syncthreads();                       // previous tile fully consumed
#pragma unroll
    for (int i = 0; i < 2; ++i){
      int c = i*256 + tid;                 // chunk id 0..511
      int r = c >> 2, p = c & 3;
      int ks = p ^ ((r >> 1) & 3);         // pre-swizzled source k-chunk
      async16(A + (size_t)(m0 + r)*K + k0 + ks*8, sA + (size_t)(i*256 + w*64)*8);
      async16(B + (size_t)(n0 + r)*K + k0 + ks*8, sB + (size_t)(i*256 + w*64)*8);
    }
    __syncthreads();                       // drains vmcnt -> LDS ready

    bf16x8 af[4], bfr[4];
#pragma unroll
    for (int mt = 0; mt < 4; ++mt){
      int row = wm*64 + mt*16 + ln;
      int p = g ^ ((row >> 1) & 3);
      af[mt] = *(const bf16x8*)&sA[row*32 + p*8];
    }
#pragma unroll
    for (int nt = 0; nt < 4; ++nt){
      int row = wn*64 + nt*16 + ln;
      int p = g ^ ((row >> 1) & 3);
      bfr[nt] = *(const bf16x8*)&sB[row*32 + p*8];
    }
    __builtin_amdgcn_s_setprio(1);
#pragma unroll
    for (int mt = 0; mt < 4; ++mt)
#pragma unroll
      for (int nt = 0; nt < 4; ++nt)
        acc[mt][nt] = __builtin_amdgcn_mfma_f32_16x16x32_bf16(af[mt], bfr[nt], acc[mt][nt], 0, 0, 0);
    __builtin_amdgcn_s_setprio(0);
  }
}

// ---------------------------------------------------------------------------
// QKV projection + bias + RoPE(Q,K) + head-split; V written transposed.
// Q is pre-scaled by log2(e)/sqrt(d) so attention needs no per-tile scaling.
// ---------------------------------------------------------------------------
#define SCQ 0.18033688011112042f   // 0.125 * log2(e)

__global__ __launch_bounds__(256) void gemm_qkv_kernel(
    const u16* __restrict__ xb,
    const u16* __restrict__ wqb, const u16* __restrict__ wkb, const u16* __restrict__ wvb,
    const float* __restrict__ bq, const float* __restrict__ bk, const float* __restrict__ bv,
    const float2* __restrict__ rope,
    u16* __restrict__ Qh, u16* __restrict__ Kh, u16* __restrict__ Vt)
{
  __shared__ u16 sA[128*32];
  __shared__ u16 sB[128*32];
  const int z = blockIdx.z;
  const u16*  W    = (z == 0) ? wqb : (z == 1) ? wkb : wvb;
  const float* bias = (z == 0) ? bq  : (z == 1) ? bk  : bv;
  const int m0 = blockIdx.y * 128, n0 = blockIdx.x * 128;

  f32x4 acc[4][4];
  gemm128_mainloop(xb, W, m0, n0, CMODEL, sA, sB, acc);

  const int tid = threadIdx.x, w = tid >> 6, lane = tid & 63;
  const int ln = lane & 15, g = lane >> 4;
  const int wm = w >> 1, wn = w & 1;

#pragma unroll
  for (int mt = 0; mt < 4; ++mt){
#pragma unroll
    for (int nt = 0; nt < 4; ++nt){
      int o  = n0 + wn*64 + nt*16 + ln;    // output feature 0..1023
      float bb = bias[o];
      int h  = o >> 6;
      int dd = o & 63;
      if (z < 2){
        int j = dd >> 1;
        u16* dst = (z == 0) ? Qh : Kh;
        float qs = (z == 0) ? SCQ : 1.0f;
#pragma unroll
        for (int rr = 0; rr < 4; ++rr){
          int t  = m0 + wm*64 + mt*16 + g*4 + rr;   // global token
          int b  = t >> 11, tt = t & (TSEQ-1);
          float v  = acc[mt][nt][rr] + bb;
          float pv = __shfl_xor(v, 1);              // rope partner (o^1), same row
          float2 cs = rope[tt*32 + j];
          float out = ((o & 1) == 0) ? (v*cs.x - pv*cs.y) : (pv*cs.y + v*cs.x);
          dst[(size_t)((b*NHEAD + h)*TSEQ + tt)*HDIM + dd] = f2bf(out * qs);
        }
      } else {
        int t0 = m0 + wm*64 + mt*16 + g*4;
        int b  = t0 >> 11, tt0 = t0 & (TSEQ-1);
        u16 pk[4];
#pragma unroll
        for (int rr = 0; rr < 4; ++rr) pk[rr] = f2bf(acc[mt][nt][rr] + bb);
        *(ushort4*)&Vt[(size_t)((b*NHEAD + h)*HDIM + dd)*TSEQ + tt0] =
            make_ushort4(pk[0], pk[1], pk[2], pk[3]);
      }
    }
  }
}

// ---------------------------------------------------------------------------
// Flash attention v4, causal.
//  - conditional max-tree: lane-local growth test; full shfl tree + rescale
//    only when some row max grows by >8 (log2 units). Common path has NO
//    cross-lane ops in softmax.
//  - hoisted jt-invariant LDS offsets (K read, V read, P read).
//  - s_setprio around MFMA clusters.
// ---------------------------------------------------------------------------
__global__ __launch_bounds__(256) void attn_kernel(
    const u16* __restrict__ Qh, const u16* __restrict__ Kh,
    const u16* __restrict__ Vt, u16* __restrict__ yb)
{
  __shared__ u16 sK[2][64*64];
  __shared__ u16 sV[2][64*64];
  __shared__ u16 plds[4][16*64];

  const int tid = threadIdx.x, w = tid >> 6, lane = tid & 63;
  const int ln = lane & 15, g = lane >> 4;

  // XCD-aware remap of the 1024-block 1D grid: bid&7 = XCD slot.
  const int bid = blockIdx.x;
  const int xcd = bid & 7, s = bid >> 3;          // s: 0..127
  const int p   = s & 15;                          // pair index 0..15
  const int bh  = xcd * 8 + (s >> 4);              // 8 bh per XCD slot
  const int b   = bh >> 4, h = bh & (NHEAD-1);

  const u16* Qbase = Qh + (size_t)bh * TSEQ * HDIM;
  const u16* Kbase = Kh + (size_t)bh * TSEQ * HDIM;
  const u16* Vbase = Vt + (size_t)bh * HDIM * TSEQ;
  u16* pw = plds[w];

  // ---- hoisted jt-invariant LDS element-offsets ----
  unsigned koff[8];                        // [nt][half]
#pragma unroll
  for (int nt = 0; nt < 4; ++nt){
    int row = nt*16 + ln;
    koff[nt*2+0] = row*64 + ((g     ^ (row&7))<<3);
    koff[nt*2+1] = row*64 + (((4+g) ^ (row&7))<<3);
  }
  unsigned voff[8];                        // [kc][dt]
#pragma unroll
  for (int kc = 0; kc < 2; ++kc)
#pragma unroll
    for (int dt = 0; dt < 4; ++dt){
      int row = dt*16 + ln;
      voff[kc*4+dt] = row*64 + (((kc*4+g) ^ (row&7))<<3);
    }
  unsigned proff[2];                       // P read
#pragma unroll
  for (int kc = 0; kc < 2; ++kc)
    proff[kc] = ln*64 + ((kc*32 + g*8) ^ ((ln & 7) << 3));

  const f32x4 zero = {0.f, 0.f, 0.f, 0.f};

  int buf = 0;
#pragma unroll 1
  for (int pi = 0; pi < 2; ++pi){
    const int qt = pi ? (31 - p) : p;      // q-tile index, 64 rows
    const int qb = qt*64 + w*16;

    bf16x8 aq[2];
#pragma unroll
    for (int kc = 0; kc < 2; ++kc)
      aq[kc] = *(const bf16x8*)&Qbase[(size_t)(qb + ln)*HDIM + kc*32 + g*8];

    f32x4 yacc[4];
#pragma unroll
    for (int dt = 0; dt < 4; ++dt) yacc[dt] = zero;
    float m2[4], lp[4];
#pragma unroll
    for (int rr = 0; rr < 4; ++rr){ m2[rr] = -1e30f; lp[rr] = 0.f; }

    // stage tile 0 of this pass
    {
      u16* sKb = sK[buf]; u16* sVb = sV[buf];
#pragma unroll
      for (int i = 0; i < 2; ++i){
        int c = i*256 + tid, r = c >> 3, pc = c & 7;
        async16(Kbase + (size_t)r*HDIM + ((pc ^ (r&7))<<3), sKb + (size_t)(i*256 + w*64)*8);
        async16(Vbase + (size_t)r*TSEQ + ((pc ^ (r&7))<<3), sVb + (size_t)(i*256 + w*64)*8);
      }
    }

#pragma unroll 1
    for (int jt = 0; jt <= qt; ++jt){
      __syncthreads();                     // drains staged loads; all waves synced
      if (jt < qt){                        // prefetch next tile into other buffer
        u16* sKb = sK[buf^1]; u16* sVb = sV[buf^1];
#pragma unroll
        for (int i = 0; i < 2; ++i){
          int c = i*256 + tid, r = c >> 3, pc = c & 7;
          async16(Kbase + (size_t)((jt+1)*64 + r)*HDIM + ((pc ^ (r&7))<<3), sKb + (size_t)(i*256 + w*64)*8);
          async16(Vbase + (size_t)r*TSEQ + (jt+1)*64 + ((pc ^ (r&7))<<3),   sVb + (size_t)(i*256 + w*64)*8);
        }
      }
      const u16* sKb = sK[buf];
      const u16* sVb = sV[buf];

      // S = Q K^T for this 64-wide kv tile (Q pre-scaled; log2 domain)
      f32x4 sc4[4];
      __builtin_amdgcn_s_setprio(1);
#pragma unroll
      for (int nt = 0; nt < 4; ++nt){
        bf16x8 k0 = *(const bf16x8*)&sKb[koff[nt*2+0]];
        bf16x8 k1 = *(const bf16x8*)&sKb[koff[nt*2+1]];
        f32x4 t = __builtin_amdgcn_mfma_f32_16x16x32_bf16(aq[0], k0, zero, 0, 0, 0);
        sc4[nt]  = __builtin_amdgcn_mfma_f32_16x16x32_bf16(aq[1], k1, t,    0, 0, 0);
      }
      __builtin_amdgcn_s_setprio(0);

      // causal mask — diagonal tile only (wave-uniform branch)
      if (jt == qt){
#pragma unroll
        for (int nt = 0; nt < 4; ++nt){
          int tk = nt*16 + ln;
#pragma unroll
          for (int rr = 0; rr < 4; ++rr)
            if (tk > w*16 + g*4 + rr) sc4[nt][rr] = -1e30f;
        }
      }

      // lane-local max per row-slot
      float lm[4];
#pragma unroll
      for (int rr = 0; rr < 4; ++rr)
        lm[rr] = fmaxf(fmaxf(sc4[0][rr], sc4[1][rr]), fmaxf(sc4[2][rr], sc4[3][rr]));

      // defer-max: full tree + rescale only when a row max grows by >8
      float growth = fmaxf(fmaxf(lm[0]-m2[0], lm[1]-m2[1]), fmaxf(lm[2]-m2[2], lm[3]-m2[3]));
      if (__any(growth > 8.0f)){
#pragma unroll
        for (int mk = 1; mk <= 8; mk <<= 1)
#pragma unroll
          for (int rr = 0; rr < 4; ++rr) lm[rr] = fmaxf(lm[rr], __shfl_xor(lm[rr], mk));
#pragma unroll
        for (int rr = 0; rr < 4; ++rr){
          float mn  = fmaxf(m2[rr], lm[rr]);
          float scl = exp2f(m2[rr] - mn);
          m2[rr] = mn;
          lp[rr] *= scl;
          yacc[0][rr] *= scl; yacc[1][rr] *= scl; yacc[2][rr] *= scl; yacc[3][rr] *= scl;
        }
      }

      // exp + per-lane partial sum + truncating pack -> per-wave LDS (XOR-swizzled)
      float ts[4] = {0.f, 0.f, 0.f, 0.f};
#pragma unroll
      for (int nt = 0; nt < 4; ++nt)
#pragma unroll
        for (int rr = 0; rr < 4; ++rr){
          float pv = exp2f(sc4[nt][rr] - m2[rr]);
          ts[rr] += pv;
          int row = g*4 + rr;
          int ec  = (nt*16 + ln) ^ ((row & 7) << 3);
          pw[row*64 + ec] = (u16)(__float_as_uint(pv) >> 16);
        }
#pragma unroll
      for (int rr = 0; rr < 4; ++rr) lp[rr] += ts[rr];

      // PV
#pragma unroll
      for (int kc = 0; kc < 2; ++kc){
        bf16x8 ap = *(const bf16x8*)&pw[proff[kc]];
        __builtin_amdgcn_s_setprio(1);
#pragma unroll
        for (int dt = 0; dt < 4; ++dt){
          bf16x8 bv = *(const bf16x8*)&sVb[voff[kc*4+dt]];
          yacc[dt] = __builtin_amdgcn_mfma_f32_16x16x32_bf16(ap, bv, yacc[dt], 0, 0, 0);
        }
        __builtin_amdgcn_s_setprio(0);
      }
      buf ^= 1;
    }

    // epilogue: reduce row sums across the 16 lanes, divide, write bf16
#pragma unroll
    for (int mk = 1; mk <= 8; mk <<= 1)
#pragma unroll
      for (int rr = 0; rr < 4; ++rr) lp[rr] += __shfl_xor(lp[rr], mk);
    float inv[4];
#pragma unroll
    for (int rr = 0; rr < 4; ++rr) inv[rr] = 1.0f / lp[rr];
#pragma unroll
    for (int dt = 0; dt < 4; ++dt)
#pragma unroll
      for (int rr = 0; rr < 4; ++rr){
        int tt = qb + g*4 + rr;
        int c  = h*HDIM + dt*16 + ln;
        yb[(size_t)(b*TSEQ + tt)*CMODEL + c] = f2bf(yacc[dt][rr] * inv[rr]);
      }
  }
}

// ---------------------------------------------------------------------------
// output projection, f32 result straight to d_out
// ---------------------------------------------------------------------------
__global__ __launch_bounds__(256) void gemm_proj_kernel(
    const u16* __restrict__ yb, const u16* __restrict__ wpb,
    const float* __restrict__ bp, float* __restrict__ out)
{
  __shared__ u16 sA[128*32];
  __shared__ u16 sB[128*32];
  const int m0 = blockIdx.y * 128, n0 = blockIdx.x * 128;
  f32x4 acc[4][4];
  gemm128_mainloop(yb, wpb, m0, n0, CMODEL, sA, sB, acc);

  const int tid = threadIdx.x, w = tid >> 6, lane = tid & 63;
  const int ln = lane & 15, g = lane >> 4;
  const int wm = w >> 1, wn = w & 1;
#pragma unroll
  for (int mt = 0; mt < 4; ++mt)
#pragma unroll
    for (int nt = 0; nt < 4; ++nt){
      int o = n0 + wn*64 + nt*16 + ln;
      float bb = bp[o];
#pragma unroll
      for (int rr = 0; rr < 4; ++rr){
        int t = m0 + wm*64 + mt*16 + g*4 + rr;
        out[(size_t)t*CMODEL + o] = acc[mt][nt][rr] + bb;
      }
    }
}

// ---------------------------------------------------------------------------
extern "C" void kernel_launch(void* const* d_in, const int* in_sizes, int n_in,
                              void* d_out, int out_size, void* d_ws, size_t ws_size,
                              hipStream_t stream)
{
  const float* x  = (const float*)d_in[0];
  const float* wq = (const float*)d_in[1];
  const float* bq = (const float*)d_in[2];
  const float* wk = (const float*)d_in[3];
  const float* bk = (const float*)d_in[4];
  const float* wv = (const float*)d_in[5];
  const float* bv = (const float*)d_in[6];
  const float* wp = (const float*)d_in[7];
  const float* bp = (const float*)d_in[8];

  char* ws = (char*)d_ws;
  u16*    xb   = (u16*)   (ws + 0);           // 16 MiB
  u16*    wqb  = (u16*)   (ws + 16777216);    // 2 MiB
  u16*    wkb  = (u16*)   (ws + 18874368);
  u16*    wvb  = (u16*)   (ws + 20971520);
  u16*    wpb  = (u16*)   (ws + 23068672);
  float2* rope = (float2*)(ws + 25165824);    // 512 KiB
  u16*    Qh   = (u16*)   (ws + 25690112);    // 16 MiB  [bh][t][d]
  u16*    Kh   = (u16*)   (ws + 42467328);    // 16 MiB  [bh][t][d]
  u16*    Vt   = (u16*)   (ws + 59244544);    // 16 MiB  [bh][d][t]
  u16*    yb   = (u16*)   (ws + 76021760);    // 16 MiB  [token][C]

  cast_bf16_kernel<<<2048, 256, 0, stream>>>(x,  xb,  MTOK*CMODEL/4);
  cast4_bf16_kernel<<<dim3(256, 4), 256, 0, stream>>>(wq, wk, wv, wp, wqb, wkb, wvb, wpb,
                                                      CMODEL*CMODEL/4);
  rope_table_kernel<<<(TSEQ*(HDIM/2) + 255)/256, 256, 0, stream>>>(rope);

  gemm_qkv_kernel<<<dim3(CMODEL/128, MTOK/128, 3), 256, 0, stream>>>(
      xb, wqb, wkb, wvb, bq, bk, bv, rope, Qh, Kh, Vt);

  attn_kernel<<<dim3(1024), 256, 0, stream>>>(Qh, Kh, Vt, yb);

  gemm_proj_kernel<<<dim3(CMODEL/128, MTOK/128), 256, 0, stream>>>(yb, wpb, bp, (float*)d_out);
}